// Round 11
// baseline (88.965 us; speedup 1.0000x reference)
//
#include <hip/hip_runtime.h>

// entmax-1.5 over last axis (K=256) of [2048,127,256] fp32.
//
// Math (verified absmax 3.9e-3 vs 2e-2 threshold): with z = x/2, tau = t/2,
// solve g(t) = sum relu(x-t)^2 = 4 by Newton from t0 = max(x)-2 (convex,
// monotone -> no overshoot), then y = (relu(x-t)/2)^2.
//
// R11: revert R10's inline-asm store (CDNA stores read data VGPRs lazily;
// inline-asm stores are invisible to the waitcnt pass, so the compiler
// reused the data regs for the next batch's loads -> raw x written to out,
// absmax 6.4). Back to compiler-modeled __builtin_nontemporal_store.
// New lever: 4-deep register prefetch -- issue all 16 dwordx4 loads
// (16KB/wave in flight) before the first solve. __launch_bounds__(256,6)
// raises the VGPR budget to ~85 so the allocator can keep xA..xD live
// (R6 lesson: it remats toward the 64-reg cliff otherwise); sched_barrier
// after each load_batch stops the scheduler sinking them.
// Confirmation: VGPR ~78-88. If dur null at ~80-84us -> MLP exhausted,
// declare practical roofline (~82% of the ~67us MALL-internal floor).
//
// Layout: 16 lanes/row, 16 elems/lane, 4 rows/batch/wave, 4 batches/wave,
// 4 waves/block. 260096 rows = 4064 blocks x 4 waves x 4 batches x 4 rows.

#define K 256
#define NITER 6

typedef float vf4 __attribute__((ext_vector_type(4)));

// lane covers cols sub*4 + k*64 .. +3 (16 lanes x 16B = 256B segments)
__device__ __forceinline__ void load_batch(const float* __restrict__ p,
                                           float x[16]) {
    #pragma unroll
    for (int k = 0; k < 4; ++k) {
        const vf4 v = *reinterpret_cast<const vf4*>(p + k * 64);
        x[k*4+0] = v.x; x[k*4+1] = v.y; x[k*4+2] = v.z; x[k*4+3] = v.w;
    }
}

__device__ __forceinline__ void solve_store(const float x[16],
                                            float* __restrict__ op) {
    // row max: per-lane tree + 4 shuffle rounds across the row's 16 lanes
    float m0 = fmaxf(x[0], x[1]);
    float m1 = fmaxf(x[2], x[3]);
    float m2 = fmaxf(x[4], x[5]);
    float m3 = fmaxf(x[6], x[7]);
    #pragma unroll
    for (int i = 8; i < 16; i += 4) {
        m0 = fmaxf(m0, x[i+0]);
        m1 = fmaxf(m1, x[i+1]);
        m2 = fmaxf(m2, x[i+2]);
        m3 = fmaxf(m3, x[i+3]);
    }
    float m = fmaxf(fmaxf(m0, m1), fmaxf(m2, m3));
    m = fmaxf(m, __shfl_xor(m, 1, 64));
    m = fmaxf(m, __shfl_xor(m, 2, 64));
    m = fmaxf(m, __shfl_xor(m, 4, 64));
    m = fmaxf(m, __shfl_xor(m, 8, 64));

    // Newton on g(t) = sum relu(x-t)^2 - 4, g'(t) = -2 sum relu(x-t)
    float t = m - 2.0f;
    #pragma unroll
    for (int it = 0; it < NITER; ++it) {
        float s1a = 0.0f, s1b = 0.0f, s2a = 0.0f, s2b = 0.0f;
        #pragma unroll
        for (int i = 0; i < 16; i += 2) {
            const float d0 = fmaxf(x[i]   - t, 0.0f);
            const float d1 = fmaxf(x[i+1] - t, 0.0f);
            s1a += d0;
            s1b += d1;
            s2a = fmaf(d0, d0, s2a);
            s2b = fmaf(d1, d1, s2b);
        }
        float s1 = s1a + s1b;
        float s2 = s2a + s2b;
        s1 += __shfl_xor(s1, 1, 64);
        s2 += __shfl_xor(s2, 1, 64);
        s1 += __shfl_xor(s1, 2, 64);
        s2 += __shfl_xor(s2, 2, 64);
        s1 += __shfl_xor(s1, 4, 64);
        s2 += __shfl_xor(s2, 4, 64);
        s1 += __shfl_xor(s1, 8, 64);
        s2 += __shfl_xor(s2, 8, 64);
        t += (s2 - 4.0f) * 0.5f * __builtin_amdgcn_rcpf(s1);
    }

    // y = (relu(x - t) / 2)^2, NT stores (compiler-modeled, hazard-safe)
    #pragma unroll
    for (int k = 0; k < 4; ++k) {
        const float d0 = fmaxf(x[k*4+0] - t, 0.0f) * 0.5f;
        const float d1 = fmaxf(x[k*4+1] - t, 0.0f) * 0.5f;
        const float d2 = fmaxf(x[k*4+2] - t, 0.0f) * 0.5f;
        const float d3 = fmaxf(x[k*4+3] - t, 0.0f) * 0.5f;
        vf4 v;
        v.x = d0 * d0;
        v.y = d1 * d1;
        v.z = d2 * d2;
        v.w = d3 * d3;
        __builtin_nontemporal_store(v, reinterpret_cast<vf4*>(op + k * 64));
    }
}

__global__ __launch_bounds__(256, 6) void entmax15_kernel(
    const float* __restrict__ in, float* __restrict__ out, int nwaves)
{
    const int lane = threadIdx.x & 63;
    const int wave = threadIdx.x >> 6;
    const int sub  = lane & 15;       // lane within row (16 lanes/row)
    const int rloc = lane >> 4;       // row within wave-batch (4 rows)
    const int g    = blockIdx.x * 4 + wave;

    const long long base    = ((long long)g * 4 + rloc) * K + sub * 4;
    const long long bstride = (long long)nwaves * 4 * K;  // elems per batch slab
    const long long off0 = base;
    const long long off1 = base + bstride;
    const long long off2 = base + 2 * bstride;
    const long long off3 = base + 3 * bstride;

    float xA[16], xB[16], xC[16], xD[16];

    // issue all 16 loads (16 KB/wave outstanding) before any solve
    load_batch(in + off0, xA);
    __builtin_amdgcn_sched_barrier(0);
    load_batch(in + off1, xB);
    __builtin_amdgcn_sched_barrier(0);
    load_batch(in + off2, xC);
    __builtin_amdgcn_sched_barrier(0);
    load_batch(in + off3, xD);
    __builtin_amdgcn_sched_barrier(0);

    solve_store(xA, out + off0);
    solve_store(xB, out + off1);
    solve_store(xC, out + off2);
    solve_store(xD, out + off3);
}

extern "C" void kernel_launch(void* const* d_in, const int* in_sizes, int n_in,
                              void* d_out, int out_size, void* d_ws, size_t ws_size,
                              hipStream_t stream)
{
    const float* in = (const float*)d_in[0];
    float* out = (float*)d_out;
    const int nrows  = in_sizes[0] / K;              // 260096
    const int nwaves = nrows / (4 * 4);              // 16256 (4 rows x 4 batches)
    const int blocks = nwaves / 4;                   // 4064
    entmax15_kernel<<<dim3(blocks), dim3(256), 0, stream>>>(in, out, nwaves);
}

// Round 12
// 81.865 us; speedup vs baseline: 1.0867x; 1.0867x over previous
//
#include <hip/hip_runtime.h>

// entmax-1.5 over last axis (K=256) of [2048,127,256] fp32.
//
// Math (verified absmax 3.9e-3 vs 2e-2 threshold): with z = x/2, tau = t/2,
// solve g(t) = sum relu(x-t)^2 = 4 by Newton from t0 = max(x)-2 (convex,
// monotone -> no overshoot), then y = (relu(x-t)/2)^2.
//
// R12: LDS-DMA staging. R6-R11 proved register-destination prefetch is
// un-pinnable: the allocator's remat pass (post-scheduling, ignores
// sched_barrier) re-issues loads at use points (R11: VGPR 40 not 84, loads
// issued twice, dur regressed). global_load_lds stages into LDS -- nothing
// to rematerialize; arrival controlled by counted s_waitcnt vmcnt(N)
// (never 0 mid-loop). Per-wave private 2x4KB double buffer, 4 batches,
// no __syncthreads. Waits: vmcnt(4),(8),(12),(8) -- DMA b is always the
// oldest outstanding group, so these are safe even if NT stores reorder.
//
// Layout: 16 lanes/row, 16 elems/lane, 4 rows/batch/wave, 4 batches/wave,
// 4 waves/block. 260096 rows = 4064 blocks x 4 waves x 4 batches x 4 rows.
// LDS: 4 waves x 2 bufs x 4KB = 32KB/block -> 5 blocks/CU (20 waves/CU).

#define K 256
#define NITER 6

typedef float vf4 __attribute__((ext_vector_type(4)));

#define WAITV(n) asm volatile("s_waitcnt vmcnt(" #n ")" ::: "memory")
#define WAITLGKM0 asm volatile("s_waitcnt lgkmcnt(0)" ::: "memory")

// 4x global_load_lds dwordx4: instruction k moves 64 lanes x 16B = 1KB.
// gp is PER-LANE (includes rloc*K + sub*4); lp is wave-uniform; HW writes
// lp + lane*16B. lane = rloc*16+sub -> LDS float idx k*256 + rloc*64 + sub*4.
__device__ __forceinline__ void dma_batch(const float* gp, float* lp) {
    #pragma unroll
    for (int k = 0; k < 4; ++k) {
        __builtin_amdgcn_global_load_lds(gp + k * 64, lp + k * 256, 16, 0, 0);
    }
}

// read this lane's 16 elems back from the staged batch
__device__ __forceinline__ void lds_read(const float* lp, int rloc, int sub,
                                         float x[16]) {
    #pragma unroll
    for (int k = 0; k < 4; ++k) {
        const vf4 v = *reinterpret_cast<const vf4*>(lp + k * 256 + rloc * 64 + sub * 4);
        x[k*4+0] = v.x; x[k*4+1] = v.y; x[k*4+2] = v.z; x[k*4+3] = v.w;
    }
}

__device__ __forceinline__ void solve_store(const float x[16],
                                            float* __restrict__ op) {
    // row max: per-lane tree + 4 shuffle rounds across the row's 16 lanes
    float m0 = fmaxf(x[0], x[1]);
    float m1 = fmaxf(x[2], x[3]);
    float m2 = fmaxf(x[4], x[5]);
    float m3 = fmaxf(x[6], x[7]);
    #pragma unroll
    for (int i = 8; i < 16; i += 4) {
        m0 = fmaxf(m0, x[i+0]);
        m1 = fmaxf(m1, x[i+1]);
        m2 = fmaxf(m2, x[i+2]);
        m3 = fmaxf(m3, x[i+3]);
    }
    float m = fmaxf(fmaxf(m0, m1), fmaxf(m2, m3));
    m = fmaxf(m, __shfl_xor(m, 1, 64));
    m = fmaxf(m, __shfl_xor(m, 2, 64));
    m = fmaxf(m, __shfl_xor(m, 4, 64));
    m = fmaxf(m, __shfl_xor(m, 8, 64));

    // Newton on g(t) = sum relu(x-t)^2 - 4, g'(t) = -2 sum relu(x-t)
    float t = m - 2.0f;
    #pragma unroll
    for (int it = 0; it < NITER; ++it) {
        float s1a = 0.0f, s1b = 0.0f, s2a = 0.0f, s2b = 0.0f;
        #pragma unroll
        for (int i = 0; i < 16; i += 2) {
            const float d0 = fmaxf(x[i]   - t, 0.0f);
            const float d1 = fmaxf(x[i+1] - t, 0.0f);
            s1a += d0;
            s1b += d1;
            s2a = fmaf(d0, d0, s2a);
            s2b = fmaf(d1, d1, s2b);
        }
        float s1 = s1a + s1b;
        float s2 = s2a + s2b;
        s1 += __shfl_xor(s1, 1, 64);
        s2 += __shfl_xor(s2, 1, 64);
        s1 += __shfl_xor(s1, 2, 64);
        s2 += __shfl_xor(s2, 2, 64);
        s1 += __shfl_xor(s1, 4, 64);
        s2 += __shfl_xor(s2, 4, 64);
        s1 += __shfl_xor(s1, 8, 64);
        s2 += __shfl_xor(s2, 8, 64);
        t += (s2 - 4.0f) * 0.5f * __builtin_amdgcn_rcpf(s1);
    }

    // y = (relu(x - t) / 2)^2, NT stores (compiler-modeled, hazard-safe)
    #pragma unroll
    for (int k = 0; k < 4; ++k) {
        const float d0 = fmaxf(x[k*4+0] - t, 0.0f) * 0.5f;
        const float d1 = fmaxf(x[k*4+1] - t, 0.0f) * 0.5f;
        const float d2 = fmaxf(x[k*4+2] - t, 0.0f) * 0.5f;
        const float d3 = fmaxf(x[k*4+3] - t, 0.0f) * 0.5f;
        vf4 v;
        v.x = d0 * d0;
        v.y = d1 * d1;
        v.z = d2 * d2;
        v.w = d3 * d3;
        __builtin_nontemporal_store(v, reinterpret_cast<vf4*>(op + k * 64));
    }
}

__global__ __launch_bounds__(256) void entmax15_kernel(
    const float* __restrict__ in, float* __restrict__ out, int nwaves)
{
    __shared__ float smem[4][2][1024];   // [wave][dbuf][4KB batch]

    const int lane = threadIdx.x & 63;
    const int wave = threadIdx.x >> 6;
    const int sub  = lane & 15;       // lane within row (16 lanes/row)
    const int rloc = lane >> 4;       // row within wave-batch (4 rows)
    const int g    = blockIdx.x * 4 + wave;

    const long long base    = ((long long)g * 4 + rloc) * K + sub * 4;
    const long long bs      = (long long)nwaves * 4 * K;   // batch-slab stride

    float* buf0 = &smem[wave][0][0];
    float* buf1 = &smem[wave][1][0];
    const float* gin = in + base;
    float x[16];

    // prologue: 2 batches in flight
    dma_batch(gin,          buf0);                  // DMA b0 (4 ops)
    dma_batch(gin + bs,     buf1);                  // DMA b1 (4 ops)

    // b=0
    WAITV(4);                                       // b0 done (b1 in flight)
    lds_read(buf0, rloc, sub, x);
    WAITLGKM0;                                      // buf0 free to overwrite
    dma_batch(gin + 2 * bs, buf0);                  // DMA b2
    solve_store(x, out + base);

    // b=1
    WAITV(8);                                       // b1 done (b2 + st0 in flight)
    lds_read(buf1, rloc, sub, x);
    WAITLGKM0;
    dma_batch(gin + 3 * bs, buf1);                  // DMA b3
    solve_store(x, out + base + bs);

    // b=2
    WAITV(12);                                      // b2 done (st0,b3,st1 may be in flight)
    lds_read(buf0, rloc, sub, x);
    solve_store(x, out + base + 2 * bs);

    // b=3
    WAITV(8);                                       // b3 done (st1,st2 may be in flight)
    lds_read(buf1, rloc, sub, x);
    solve_store(x, out + base + 3 * bs);
}

extern "C" void kernel_launch(void* const* d_in, const int* in_sizes, int n_in,
                              void* d_out, int out_size, void* d_ws, size_t ws_size,
                              hipStream_t stream)
{
    const float* in = (const float*)d_in[0];
    float* out = (float*)d_out;
    const int nrows  = in_sizes[0] / K;              // 260096
    const int nwaves = nrows / (4 * 4);              // 16256 (4 rows x 4 batches)
    const int blocks = nwaves / 4;                   // 4064
    entmax15_kernel<<<dim3(blocks), dim3(256), 0, stream>>>(in, out, nwaves);
}